// Round 7
// baseline (10138.206 us; speedup 1.0000x reference)
//
#include <hip/hip_runtime.h>
#include <hip/hip_bf16.h>
#include <math.h>

// LSTM decoder: B=64, T=512, IN=256, OUT=256, H=1024, 2 layers + linear head.
// Round 11: attack load-latency starvation (R10 proved barrier wait is only
// ~3.8us/step; the rest is phase-load stalls at 25% occupancy).
//  - 1024-thread blocks (16 waves = 8 K-split x 2 batch-half): occupancy
//    25%->50%, per-wave load chains halved, 2x miss concurrency per CU.
//  - inv pre-window (R8-proven placement); x[t+1] prefetch restored in the
//    window (waves 8..15, exact next-A addresses) - survives into A(t+1)
//    since the next inv is after A(t+1).
//  - Poll phase has NO fence (per-XCD L2 inv already done pre-window; no
//    h-slot lines are read between inv and release).
//  - Barrier: R9 hierarchical release (aggregator all-256 poll -> release
//    word per XCD; followers poll one word), s_sleep polls (R10 spin hurt).

typedef __attribute__((ext_vector_type(8))) short bf16x8;   // 8 x bf16
typedef __attribute__((ext_vector_type(4))) float f32x4;
typedef unsigned long long u64;

__device__ __forceinline__ float sigm(float v) {
  return 1.f / (1.f + __expf(-v));
}
__device__ __forceinline__ float ftanh(float v) {
  return 2.f / (1.f + __expf(-2.f * v)) - 1.f;
}

__device__ __forceinline__ unsigned short bf16_bits(float v) {
  __hip_bfloat16 hb = __float2bfloat16(v);
  unsigned short us;
  __builtin_memcpy(&us, &hb, 2);
  return us;
}

// write-through (sc0 sc1) 2B store
__device__ __forceinline__ void vstore_bf16(__hip_bfloat16* p, float v) {
  *(volatile unsigned short*)p = bf16_bits(v);
}

// ---------------- prep kernels (one-time per launch) ----------------

// W0cat[u*4+g][k] : k<256 -> Wih0[g*1024+u][k], else Whh0[g*1024+u][k-256]
__global__ __launch_bounds__(256) void prep_w0(const float* __restrict__ Wih0,
                                               const float* __restrict__ Whh0,
                                               __hip_bfloat16* __restrict__ W0) {
  const unsigned n = 4096u * 1280u;
  for (unsigned d = blockIdx.x * blockDim.x + threadIdx.x; d < n;
       d += blockDim.x * gridDim.x) {
    unsigned r = d / 1280u;
    unsigned k = d - r * 1280u;
    unsigned u = r >> 2, g = r & 3u;
    unsigned srow = g * 1024u + u;
    float v = (k < 256u) ? Wih0[(size_t)srow * 256u + k]
                         : Whh0[(size_t)srow * 1024u + (k - 256u)];
    W0[d] = __float2bfloat16(v);
  }
}

// W1ext[4352][2048]: rows<4096 reordered LSTM1 weights [Wih1|Whh1];
// rows 4096+o: [zeros(1024) | Wlin[o]]
__global__ __launch_bounds__(256) void prep_w1(const float* __restrict__ Wih1,
                                               const float* __restrict__ Whh1,
                                               const float* __restrict__ Wlin,
                                               __hip_bfloat16* __restrict__ W1) {
  const unsigned n = 4352u * 2048u;
  for (unsigned d = blockIdx.x * blockDim.x + threadIdx.x; d < n;
       d += blockDim.x * gridDim.x) {
    unsigned r = d >> 11;
    unsigned k = d & 2047u;
    float v;
    if (r < 4096u) {
      unsigned u = r >> 2, g = r & 3u;
      unsigned srow = g * 1024u + u;
      v = (k < 1024u) ? Wih1[(size_t)srow * 1024u + k]
                      : Whh1[(size_t)srow * 1024u + (k - 1024u)];
    } else {
      unsigned o = r - 4096u;
      v = (k < 1024u) ? 0.f : Wlin[(size_t)o * 1024u + (k - 1024u)];
    }
    W1[d] = __float2bfloat16(v);
  }
}

// xbf[t][b][k] = bf16( t==0 ? 0 : x[b][t-1][k] )   (teacher forcing shift)
__global__ __launch_bounds__(256) void prep_x(const float* __restrict__ x,
                                              __hip_bfloat16* __restrict__ xbf) {
  const unsigned n = 512u * 64u * 256u;
  for (unsigned d = blockIdx.x * blockDim.x + threadIdx.x; d < n;
       d += blockDim.x * gridDim.x) {
    unsigned t = d >> 14;
    unsigned b = (d >> 8) & 63u;
    unsigned k = d & 255u;
    float v = (t == 0u) ? 0.f : x[((size_t)b * 512u + (t - 1u)) * 256u + k];
    xbf[d] = __float2bfloat16(v);
  }
}

// biases (gate-interleaved, bih+bhh combined) + h init: h0[-1] -> slot 0,
// h1[-1] -> slot 2 (h1[tau] lives in slot tau%3; tau=-1 -> 2)
__global__ __launch_bounds__(256) void prep_misc(
    const float* __restrict__ bih0, const float* __restrict__ bhh0,
    const float* __restrict__ bih1, const float* __restrict__ bhh1,
    const float* __restrict__ z, float* __restrict__ b0, float* __restrict__ b1,
    __hip_bfloat16* __restrict__ h0buf, __hip_bfloat16* __restrict__ h1buf) {
  for (int i = blockIdx.x * blockDim.x + threadIdx.x; i < 73728;
       i += blockDim.x * gridDim.x) {
    if (i < 4096) {
      int u = i >> 2, g = i & 3;
      b0[i] = bih0[g * 1024 + u] + bhh0[g * 1024 + u];
    } else if (i < 8192) {
      int r = i - 4096;
      int u = r >> 2, g = r & 3;
      b1[r] = bih1[g * 1024 + u] + bhh1[g * 1024 + u];
    } else {
      int j = i - 8192;  // 0..65535
      float zv = z[j];
      vstore_bf16(h0buf + j, zv);                       // h0 slot 0
      vstore_bf16(h1buf + 2 * 65536 + j, zv);           // h1 slot 2
    }
  }
}

// ---------------- projection helper (blocks 64..127) ----------------
// out[pbat*16 .. +16, t_out, pcol*16 .. +16) = h1p @ Wlin^T + blin
// 1024-thread blocks: waves 0..7 compute (K-split 8), all 16 waves sync.

__device__ __forceinline__ void do_proj(const __hip_bfloat16* __restrict__ h1p,
                                        const bf16x8* wp, float (*red)[16][68],
                                        const float* __restrict__ blin,
                                        float* __restrict__ out, int pcol,
                                        int pbat, int t_out, int tid, int w,
                                        int col, int kq) {
  if (w < 8) {
    f32x4 a0 = {0.f, 0.f, 0.f, 0.f};
    const __hip_bfloat16* ab =
        h1p + ((size_t)((pbat << 4) + col) << 10) + (w << 7) + (kq << 3);
#pragma unroll
    for (int c = 0; c < 4; ++c) {
      bf16x8 f = *(const bf16x8*)(ab + (c << 5));
      a0 = __builtin_amdgcn_mfma_f32_16x16x32_bf16(f, wp[c], a0, 0, 0, 0);
    }
    *(f32x4*)&red[w][col][(kq << 2)] = a0;
  }
  __syncthreads();
  if (tid < 256) {
    int o_l = tid & 15, b = tid >> 4;  // b: 0..15
    float v = blin[(pcol << 4) + o_l];
#pragma unroll
    for (int ww = 0; ww < 8; ++ww) v += red[ww][o_l][b];
    out[(((size_t)((pbat << 4) + b) << 9) + (size_t)t_out) * 256 + (pcol << 4) +
        o_l] = v;
  }
  // no trailing sync: every call site is followed by a block-wide barrier
  // before red is written again.
}

// ---------------- persistent kernel ----------------

__global__ __launch_bounds__(1024, 4) void k_persist(
    const __hip_bfloat16* __restrict__ xbf, const __hip_bfloat16* __restrict__ W0,
    const __hip_bfloat16* __restrict__ W1, const float* __restrict__ b0,
    const float* __restrict__ b1, const float* __restrict__ blin,
    __hip_bfloat16* __restrict__ h0buf, __hip_bfloat16* __restrict__ h1buf,
    float* __restrict__ out, unsigned* __restrict__ flags) {
  const int tid = threadIdx.x;
  const int lane = tid & 63;
  const int w = tid >> 6;          // wave id 0..15
  const int ks = w >> 1;           // K-split index 0..7
  const int bh = w & 1;            // batch half 0..1
  const int bid = blockIdx.x;
  const int cb = bid << 4;         // 16 gate-columns owned by this block
  const int col = lane & 15;
  const int kq = lane >> 4;
  const int n = cb + col;
  const int brow = (bh << 5) + col;  // batch-row base for f0
  const bool isproj = (bid >= 64 && bid < 128);
  const int pcol = bid & 15;       // proj: out-col tile
  const int pbat = (bid >> 4) & 3; // proj: batch tile

  // ---- per-XCD aggregator election ----
  // flags layout (words): [0..255] flags; [256..263] lead; [272+16x] release.
  __shared__ int s_agg, s_lead, s_xcd;
  {
    unsigned* lead = flags + 256;
    if (tid == 0) {
      unsigned xcc = 0;
      asm volatile("s_getreg_b32 %0, hwreg(HW_REG_XCC_ID)" : "=s"(xcc));
      xcc &= 7u;
      unsigned old = __hip_atomic_fetch_add(&lead[xcc], 1u, __ATOMIC_RELAXED,
                                            __HIP_MEMORY_SCOPE_AGENT);
      s_agg = (old == 0u) ? 1 : 0;
      s_lead = (old == 0u || bid >= 248) ? 1 : 0;  // inv duty (belt: bid>=248)
      s_xcd = (int)xcc;
    }
  }

  // ---- weights -> registers (persist across all 512 steps) ----
  bf16x8 wa[5], wb[8], wp[4];
  {
    const __hip_bfloat16* p = W0 + (size_t)n * 1280 + ks * 160 + (kq << 3);
#pragma unroll
    for (int c = 0; c < 5; ++c) wa[c] = *(const bf16x8*)(p + (c << 5));
  }
  {
    const __hip_bfloat16* p = W1 + ((size_t)n << 11) + (ks << 8) + (kq << 3);
#pragma unroll
    for (int c = 0; c < 8; ++c) wb[c] = *(const bf16x8*)(p + (c << 5));
  }
  if (isproj && w < 8) {
    const __hip_bfloat16* p = W1 +
        ((size_t)(4096 + (pcol << 4) + col) << 11) + 1024 + (w << 7) + (kq << 3);
#pragma unroll
    for (int c = 0; c < 4; ++c) wp[c] = *(const bf16x8*)(p + (c << 5));
  } else {
#pragma unroll
    for (int c = 0; c < 4; ++c) wp[c] = bf16x8{0, 0, 0, 0, 0, 0, 0, 0};
  }

  // cell threads: tid<256 own (unit u_l of 4, batch bq); c-state in registers
  const int u_l = tid & 3, bq = tid >> 2;
  float bias0[4], bias1[4];
  if (tid < 256) {
#pragma unroll
    for (int g = 0; g < 4; ++g) {
      bias0[g] = b0[cb + (u_l << 2) + g];
      bias1[g] = b1[cb + (u_l << 2) + g];
    }
  }
  float c0v = 0.f, c1v = 0.f;

  __shared__ float red[8][16][68];  // [K-split][gatecol][batch]; 68 = align

  __syncthreads();  // s_agg/s_lead/s_xcd visible to all waves

  unsigned* rel = flags + 272 + (s_xcd << 4);  // this XCD's release word

  for (int t = 0; t < 512; ++t) {
    const __hip_bfloat16* h0prev = h0buf + ((size_t)(t & 1) << 16);
    const __hip_bfloat16* h0cur = h0buf + ((size_t)((t + 1) & 1) << 16);
    const __hip_bfloat16* h1prev = h1buf + ((size_t)((t + 2) % 3) << 16);

    // ======== phase A: gates0 = [x_t | h0prev] @ W0cat^T ========
    // h0prev L2-warm from B(t-1); x_t L2-warm from last step's prefetch.
    {
      f32x4 a0 = {0.f, 0.f, 0.f, 0.f}, a1 = a0;
#pragma unroll
      for (int c = 0; c < 5; ++c) {
        const int k0 = ks * 160 + (c << 5);
        const __hip_bfloat16* ab;
        size_t rs;
        if (k0 < 256) {  // x part
          ab = xbf + ((size_t)t << 14) + k0 + (kq << 3);
          rs = 256;
        } else {         // h part
          ab = h0prev + (k0 - 256) + (kq << 3);
          rs = 1024;
        }
        bf16x8 f0 = *(const bf16x8*)(ab + (size_t)brow * rs);
        bf16x8 f1 = *(const bf16x8*)(ab + (size_t)(16 + brow) * rs);
        a0 = __builtin_amdgcn_mfma_f32_16x16x32_bf16(f0, wa[c], a0, 0, 0, 0);
        a1 = __builtin_amdgcn_mfma_f32_16x16x32_bf16(f1, wa[c], a1, 0, 0, 0);
      }
      *(f32x4*)&red[ks][col][(bh << 5) + (kq << 2)] = a0;
      *(f32x4*)&red[ks][col][(bh << 5) + 16 + (kq << 2)] = a1;
    }
    __syncthreads();
    if (tid < 256) {  // 8-way K-reduce + LSTM cell 0 -> direct 2B publish
      float gg[4];
#pragma unroll
      for (int g = 0; g < 4; ++g) {
        float v = bias0[g];
#pragma unroll
        for (int ww = 0; ww < 8; ++ww) v += red[ww][(u_l << 2) + g][bq];
        gg[g] = v;
      }
      float cn = sigm(gg[1]) * c0v + sigm(gg[0]) * ftanh(gg[2]);
      c0v = cn;
      vstore_bf16((__hip_bfloat16*)h0cur + ((size_t)bq << 10) + (cb >> 2) + u_l,
                  sigm(gg[3]) * ftanh(cn));
    }
    __syncthreads();  // red free; publish stores issued

    // ---- cache hygiene PRE-window (R8-proven placement) ----
    if (w == 0) {
      __builtin_amdgcn_sched_barrier(0);
      if (s_lead) {
        // full agent acquire: waitcnt + L1/L2 inv (proven codegen R5/R6/R8)
        __builtin_amdgcn_fence(__ATOMIC_ACQUIRE, "agent");
      } else {
        asm volatile("buffer_inv" ::: "memory");  // L1-only inv, drain-free
      }
      __builtin_amdgcn_sched_barrier(0);
    }
    __syncthreads();  // inv ordered before window reads / B loads

    // ---- window work: x[t+1] L2-prefetch (waves 8..15, survives into
    //      A(t+1) since next inv is post-A(t+1)) + proj out[t-2] ----
    if (w >= 8 && t < 511) {
      const int pks = (w - 8) >> 1, pbh = (w - 8) & 1;
      const int prow = (pbh << 5) + col;
      const __hip_bfloat16* xb = xbf + ((size_t)(t + 1) << 14);
#pragma unroll
      for (int c = 0; c < 5; ++c) {
        const int k0 = pks * 160 + (c << 5);
        if (k0 < 256) {
          const __hip_bfloat16* abx = xb + k0 + (kq << 3);
          unsigned v0 = *(const unsigned*)(abx + (size_t)prow * 256);
          unsigned v1 = *(const unsigned*)(abx + (size_t)(16 + prow) * 256);
          asm volatile("" ::"v"(v0), "v"(v1));  // keep the loads
        }
      }
    }
    if (isproj && t >= 2) {
      // h1[t-2] lives in slot (t-2)%3 == (t+1)%3; fresh (last write B(t-2),
      // inv(t-1) and inv(t) both postdate it).
      do_proj(h1buf + (((size_t)((t + 1) % 3)) << 16), wp, red, blin, out,
              pcol, pbat, t - 2, tid, w, col, kq);
    }

    // ---- drain + arrive + hierarchical release (no fence in poll) ----
    __builtin_amdgcn_s_waitcnt(0);  // per-wave: publishes / proj-outs drained
    __syncthreads();                // all waves drained before the flag
    if (tid == 0)
      __hip_atomic_store(&flags[bid], (unsigned)(t + 1), __ATOMIC_RELAXED,
                         __HIP_MEMORY_SCOPE_AGENT);
    if (w == 0) {
      const unsigned tgt = (unsigned)(t + 1);
      if (s_agg) {
        // aggregator: the ONLY all-256 poller on this XCD
        const u64* fq = (const u64*)flags;
        for (;;) {
          u64 q0 = __hip_atomic_load(&fq[2 * lane], __ATOMIC_RELAXED,
                                     __HIP_MEMORY_SCOPE_AGENT);
          u64 q1 = __hip_atomic_load(&fq[2 * lane + 1], __ATOMIC_RELAXED,
                                     __HIP_MEMORY_SCOPE_AGENT);
          int ok = ((unsigned)q0 >= tgt) & ((unsigned)(q0 >> 32) >= tgt) &
                   ((unsigned)q1 >= tgt) & ((unsigned)(q1 >> 32) >= tgt);
          if (__all(ok)) break;
          __builtin_amdgcn_s_sleep(1);
        }
        if (lane == 0)
          __hip_atomic_store(rel, tgt, __ATOMIC_RELAXED,
                             __HIP_MEMORY_SCOPE_AGENT);
      } else {
        // followers poll ONE word: their XCD's release line
        while (__hip_atomic_load(rel, __ATOMIC_RELAXED,
                                 __HIP_MEMORY_SCOPE_AGENT) < tgt)
          __builtin_amdgcn_s_sleep(1);
      }
    }
    __syncthreads();

    // ======== phase B: gates1 = [h0cur | h1prev] @ W1^T ========
    // Slot lines were dropped by this XCD's pre-window inv and NOT re-read
    // between inv and release -> refills are LLC-fresh.
    {
      const __hip_bfloat16* ab =
          ((ks < 4) ? h0cur + (ks << 8) : h1prev + ((ks - 4) << 8)) + (kq << 3);
      f32x4 a0 = {0.f, 0.f, 0.f, 0.f}, a1 = a0;
#pragma unroll
      for (int c = 0; c < 8; ++c) {
        const __hip_bfloat16* p = ab + (c << 5);
        bf16x8 f0 = *(const bf16x8*)(p + ((size_t)brow << 10));
        bf16x8 f1 = *(const bf16x8*)(p + ((size_t)(16 + brow) << 10));
        a0 = __builtin_amdgcn_mfma_f32_16x16x32_bf16(f0, wb[c], a0, 0, 0, 0);
        a1 = __builtin_amdgcn_mfma_f32_16x16x32_bf16(f1, wb[c], a1, 0, 0, 0);
      }
      *(f32x4*)&red[ks][col][(bh << 5) + (kq << 2)] = a0;
      *(f32x4*)&red[ks][col][(bh << 5) + 16 + (kq << 2)] = a1;
    }
    __syncthreads();
    if (tid < 256) {  // 8-way K-reduce + LSTM cell 1 -> direct 2B publish
      float gg[4];
#pragma unroll
      for (int g = 0; g < 4; ++g) {
        float v = bias1[g];
#pragma unroll
        for (int ww = 0; ww < 8; ++ww) v += red[ww][(u_l << 2) + g][bq];
        gg[g] = v;
      }
      float cn = sigm(gg[1]) * c1v + sigm(gg[0]) * ftanh(gg[2]);
      c1v = cn;
      // h1[t] -> slot t%3 (drains at next step's pre-flag waitcnt)
      vstore_bf16(h1buf + ((size_t)(t % 3) << 16) + ((size_t)bq << 10) +
                      (cb >> 2) + u_l,
                  sigm(gg[3]) * ftanh(cn));
    }
    __syncthreads();  // red safe for next iteration's phase A
  }

  // ---- tail: h1[510] in slot 0, h1[511] in slot 1 (just published) ----
  __builtin_amdgcn_s_waitcnt(0);  // per-wave drain of h1[511] publishes
  __syncthreads();
  if (tid == 0)
    __hip_atomic_store(&flags[bid], 513u, __ATOMIC_RELAXED,
                       __HIP_MEMORY_SCOPE_AGENT);
  if (w == 0 && s_agg) {
    const u64* fq = (const u64*)flags;
    for (;;) {
      u64 q0 = __hip_atomic_load(&fq[2 * lane], __ATOMIC_RELAXED,
                                 __HIP_MEMORY_SCOPE_AGENT);
      u64 q1 = __hip_atomic_load(&fq[2 * lane + 1], __ATOMIC_RELAXED,
                                 __HIP_MEMORY_SCOPE_AGENT);
      int ok = ((unsigned)q0 >= 513u) & ((unsigned)(q0 >> 32) >= 513u) &
               ((unsigned)q1 >= 513u) & ((unsigned)(q1 >> 32) >= 513u);
      if (__all(ok)) break;
      __builtin_amdgcn_s_sleep(1);
    }
    __builtin_amdgcn_fence(__ATOMIC_ACQUIRE, "agent");  // slot-1 may be stale
    if (lane == 0)
      __hip_atomic_store(rel, 513u, __ATOMIC_RELAXED,
                         __HIP_MEMORY_SCOPE_AGENT);
  }
  if (!isproj) return;
  if (w == 0 && !s_agg) {
    while (__hip_atomic_load(rel, __ATOMIC_RELAXED,
                             __HIP_MEMORY_SCOPE_AGENT) < 513u)
      __builtin_amdgcn_s_sleep(1);
    // one-time full acquire before reading h1[510]/h1[511]
    __builtin_amdgcn_fence(__ATOMIC_ACQUIRE, "agent");
  }
  __syncthreads();
  do_proj(h1buf, wp, red, blin, out, pcol, pbat, 510, tid, w, col, kq);
  __syncthreads();  // red reuse barrier between the two tail projections
  do_proj(h1buf + ((size_t)1 << 16), wp, red, blin, out, pcol, pbat, 511, tid,
          w, col, kq);
}

// ---------------- host launch ----------------

extern "C" void kernel_launch(void* const* d_in, const int* in_sizes, int n_in,
                              void* d_out, int out_size, void* d_ws, size_t ws_size,
                              hipStream_t stream) {
  const float* z = (const float*)d_in[0];
  const float* x = (const float*)d_in[1];
  const float* Wih0 = (const float*)d_in[2];
  const float* Whh0 = (const float*)d_in[3];
  const float* bih0 = (const float*)d_in[4];
  const float* bhh0 = (const float*)d_in[5];
  const float* Wih1 = (const float*)d_in[6];
  const float* Whh1 = (const float*)d_in[7];
  const float* bih1 = (const float*)d_in[8];
  const float* bhh1 = (const float*)d_in[9];
  const float* Wlin = (const float*)d_in[10];
  const float* blin = (const float*)d_in[11];
  float* out = (float*)d_out;

  char* ws = (char*)d_ws;
  __hip_bfloat16* W0 = (__hip_bfloat16*)(ws);                // 10,485,760 B
  __hip_bfloat16* W1 = (__hip_bfloat16*)(ws + 10485760);     // 17,825,792 B
  __hip_bfloat16* xbf = (__hip_bfloat16*)(ws + 28311552);    // 16,777,216 B
  float* b0 = (float*)(ws + 45088768);                       // 16,384 B
  float* b1 = (float*)(ws + 45105152);                       // 16,384 B
  __hip_bfloat16* h0buf = (__hip_bfloat16*)(ws + 45121536);  // 262,144 B (2 slots)
  __hip_bfloat16* h1buf = (__hip_bfloat16*)(ws + 45383680);  // 393,216 B (3 slots)
  unsigned* flags = (unsigned*)(ws + 45776896);              // 4,096 B

  hipMemsetAsync(flags, 0, 4096, stream);  // ws is re-poisoned every call
  prep_w0<<<4096, 256, 0, stream>>>(Wih0, Whh0, W0);
  prep_w1<<<4096, 256, 0, stream>>>(Wih1, Whh1, Wlin, W1);
  prep_x<<<4096, 256, 0, stream>>>(x, xbf);
  prep_misc<<<288, 256, 0, stream>>>(bih0, bhh0, bih1, bhh1, z, b0, b1, h0buf,
                                     h1buf);

  k_persist<<<256, 1024, 0, stream>>>(xbf, W0, W1, b0, b1, blin, h0buf, h1buf,
                                      out, flags);
}

// Round 8
// 9241.803 us; speedup vs baseline: 1.0970x; 1.0970x over previous
//
#include <hip/hip_runtime.h>
#include <hip/hip_bf16.h>
#include <math.h>

// LSTM decoder: B=64, T=512, IN=256, OUT=256, H=1024, 2 layers + linear head.
// Round 12: LAYER-SKEW pipeline. At iteration k, X-half (bid<128) computes
// layer-0 A(k) while Y-half (bid>=128) computes layer-1 B(k-1) — the two
// phases that were serial on every block now run concurrently on disjoint
// halves. Each block: ONE phase + ONE cell + ONE publish/drain per step
// (was two of each). One barrier per iteration (R9 hierarchical release,
// unchanged). Slots: h0 2-buf (read k&1, write (k+1)&1); h1 3-buf (B reads
// (k+1)%3, proj reads k%3, write (k+2)%3 — all distinct).
// Proj on X blocks 64..127 (lighter half), out(k-3); tails post-loop.

typedef __attribute__((ext_vector_type(8))) short bf16x8;   // 8 x bf16
typedef __attribute__((ext_vector_type(4))) float f32x4;
typedef unsigned long long u64;

__device__ __forceinline__ float sigm(float v) {
  return 1.f / (1.f + __expf(-v));
}
__device__ __forceinline__ float ftanh(float v) {
  return 2.f / (1.f + __expf(-2.f * v)) - 1.f;
}

__device__ __forceinline__ unsigned short bf16_bits(float v) {
  __hip_bfloat16 hb = __float2bfloat16(v);
  unsigned short us;
  __builtin_memcpy(&us, &hb, 2);
  return us;
}

// write-through (sc0 sc1) 2B store
__device__ __forceinline__ void vstore_bf16(__hip_bfloat16* p, float v) {
  *(volatile unsigned short*)p = bf16_bits(v);
}

// ---------------- prep kernels (one-time per launch) ----------------

// W0cat[u*4+g][k] : k<256 -> Wih0[g*1024+u][k], else Whh0[g*1024+u][k-256]
__global__ __launch_bounds__(256) void prep_w0(const float* __restrict__ Wih0,
                                               const float* __restrict__ Whh0,
                                               __hip_bfloat16* __restrict__ W0) {
  const unsigned n = 4096u * 1280u;
  for (unsigned d = blockIdx.x * blockDim.x + threadIdx.x; d < n;
       d += blockDim.x * gridDim.x) {
    unsigned r = d / 1280u;
    unsigned k = d - r * 1280u;
    unsigned u = r >> 2, g = r & 3u;
    unsigned srow = g * 1024u + u;
    float v = (k < 256u) ? Wih0[(size_t)srow * 256u + k]
                         : Whh0[(size_t)srow * 1024u + (k - 256u)];
    W0[d] = __float2bfloat16(v);
  }
}

// W1ext[4352][2048]: rows<4096 reordered LSTM1 weights [Wih1|Whh1];
// rows 4096+o: [zeros(1024) | Wlin[o]]
__global__ __launch_bounds__(256) void prep_w1(const float* __restrict__ Wih1,
                                               const float* __restrict__ Whh1,
                                               const float* __restrict__ Wlin,
                                               __hip_bfloat16* __restrict__ W1) {
  const unsigned n = 4352u * 2048u;
  for (unsigned d = blockIdx.x * blockDim.x + threadIdx.x; d < n;
       d += blockDim.x * gridDim.x) {
    unsigned r = d >> 11;
    unsigned k = d & 2047u;
    float v;
    if (r < 4096u) {
      unsigned u = r >> 2, g = r & 3u;
      unsigned srow = g * 1024u + u;
      v = (k < 1024u) ? Wih1[(size_t)srow * 1024u + k]
                      : Whh1[(size_t)srow * 1024u + (k - 1024u)];
    } else {
      unsigned o = r - 4096u;
      v = (k < 1024u) ? 0.f : Wlin[(size_t)o * 1024u + (k - 1024u)];
    }
    W1[d] = __float2bfloat16(v);
  }
}

// xbf[t][b][k] = bf16( t==0 ? 0 : x[b][t-1][k] )   (teacher forcing shift)
__global__ __launch_bounds__(256) void prep_x(const float* __restrict__ x,
                                              __hip_bfloat16* __restrict__ xbf) {
  const unsigned n = 512u * 64u * 256u;
  for (unsigned d = blockIdx.x * blockDim.x + threadIdx.x; d < n;
       d += blockDim.x * gridDim.x) {
    unsigned t = d >> 14;
    unsigned b = (d >> 8) & 63u;
    unsigned k = d & 255u;
    float v = (t == 0u) ? 0.f : x[((size_t)b * 512u + (t - 1u)) * 256u + k];
    xbf[d] = __float2bfloat16(v);
  }
}

// biases (gate-interleaved, bih+bhh combined) + h init: h0[-1] -> slot 0,
// h1[-1] -> slot 2 (h1[tau] lives in slot tau%3; tau=-1 -> 2)
__global__ __launch_bounds__(256) void prep_misc(
    const float* __restrict__ bih0, const float* __restrict__ bhh0,
    const float* __restrict__ bih1, const float* __restrict__ bhh1,
    const float* __restrict__ z, float* __restrict__ b0, float* __restrict__ b1,
    __hip_bfloat16* __restrict__ h0buf, __hip_bfloat16* __restrict__ h1buf) {
  for (int i = blockIdx.x * blockDim.x + threadIdx.x; i < 73728;
       i += blockDim.x * gridDim.x) {
    if (i < 4096) {
      int u = i >> 2, g = i & 3;
      b0[i] = bih0[g * 1024 + u] + bhh0[g * 1024 + u];
    } else if (i < 8192) {
      int r = i - 4096;
      int u = r >> 2, g = r & 3;
      b1[r] = bih1[g * 1024 + u] + bhh1[g * 1024 + u];
    } else {
      int j = i - 8192;  // 0..65535
      float zv = z[j];
      vstore_bf16(h0buf + j, zv);                       // h0 slot 0
      vstore_bf16(h1buf + 2 * 65536 + j, zv);           // h1 slot 2
    }
  }
}

// ---------------- projection helper (X blocks 64..127) ----------------
// out[pbat*16 .. +16, t_out, pcol*16 .. +16) = h1p @ Wlin^T + blin
// 8 waves = K-split 8 over K=1024.

__device__ __forceinline__ void do_proj(const __hip_bfloat16* __restrict__ h1p,
                                        const bf16x8* wp, float (*red)[16][68],
                                        const float* __restrict__ blin,
                                        float* __restrict__ out, int pcol,
                                        int pbat, int t_out, int tid, int w,
                                        int col, int kq) {
  f32x4 a0 = {0.f, 0.f, 0.f, 0.f};
  const __hip_bfloat16* ab =
      h1p + ((size_t)((pbat << 4) + col) << 10) + (w << 7) + (kq << 3);
#pragma unroll
  for (int c = 0; c < 4; ++c) {
    bf16x8 f = *(const bf16x8*)(ab + (c << 5));
    a0 = __builtin_amdgcn_mfma_f32_16x16x32_bf16(f, wp[c], a0, 0, 0, 0);
  }
  *(f32x4*)&red[w][col][(kq << 2)] = a0;
  __syncthreads();
  if (tid < 256) {
    int o_l = tid & 15, b = tid >> 4;  // b: 0..15
    float v = blin[(pcol << 4) + o_l];
#pragma unroll
    for (int ww = 0; ww < 8; ++ww) v += red[ww][o_l][b];
    out[(((size_t)((pbat << 4) + b) << 9) + (size_t)t_out) * 256 + (pcol << 4) +
        o_l] = v;
  }
  // callers follow with a block-wide barrier before red is rewritten
}

// ---------------- persistent kernel ----------------

__global__ __launch_bounds__(512) void k_persist(
    const __hip_bfloat16* __restrict__ xbf, const __hip_bfloat16* __restrict__ W0,
    const __hip_bfloat16* __restrict__ W1, const float* __restrict__ b0,
    const float* __restrict__ b1, const float* __restrict__ blin,
    __hip_bfloat16* __restrict__ h0buf, __hip_bfloat16* __restrict__ h1buf,
    float* __restrict__ out, unsigned* __restrict__ flags) {
  const int tid = threadIdx.x;
  const int lane = tid & 63;
  const int w = tid >> 6;          // wave id 0..7
  const int ks = w >> 1;           // K-split 0..3
  const int ch = w & 1;            // column half 0..1
  const int bid = blockIdx.x;
  const int col = lane & 15;
  const int kq = lane >> 4;
  const bool isX = (bid < 128);          // layer-0 half
  const bool isproj = (bid >= 64 && bid < 128);
  const int pcol = bid & 15;             // proj tile
  const int pbat = (bid >> 4) & 3;

  // ---- per-XCD aggregator election ----
  // flags layout (words): [0..255] flags; [256..263] lead; [272+16x] release.
  __shared__ int s_agg, s_xcd;
  {
    unsigned* lead = flags + 256;
    if (tid == 0) {
      unsigned xcc = 0;
      asm volatile("s_getreg_b32 %0, hwreg(HW_REG_XCC_ID)" : "=s"(xcc));
      xcc &= 7u;
      unsigned old = __hip_atomic_fetch_add(&lead[xcc], 1u, __ATOMIC_RELAXED,
                                            __HIP_MEMORY_SCOPE_AGENT);
      s_agg = (old == 0u) ? 1 : 0;
      s_xcd = (int)xcc;
    }
  }

  // ---- weights -> registers ----
  bf16x8 wa[10], wb[16], wp[4];
  if (isX) {
    const int gcol = (bid << 5) + (ch << 4) + col;  // gate-col of layer 0
    const __hip_bfloat16* p = W0 + (size_t)gcol * 1280 + ks * 320 + (kq << 3);
#pragma unroll
    for (int c = 0; c < 10; ++c) wa[c] = *(const bf16x8*)(p + (c << 5));
    if (isproj) {
      const __hip_bfloat16* q = W1 +
          ((size_t)(4096 + (pcol << 4) + col) << 11) + 1024 + (w << 7) +
          (kq << 3);
#pragma unroll
      for (int c = 0; c < 4; ++c) wp[c] = *(const bf16x8*)(q + (c << 5));
    } else {
#pragma unroll
      for (int c = 0; c < 4; ++c) wp[c] = bf16x8{0, 0, 0, 0, 0, 0, 0, 0};
    }
  } else {
    const int gcol = ((bid - 128) << 5) + (ch << 4) + col;  // gate-col layer 1
    const __hip_bfloat16* p = W1 + ((size_t)gcol << 11) + (ks << 9) + (kq << 3);
#pragma unroll
    for (int c = 0; c < 16; ++c) wb[c] = *(const bf16x8*)(p + (c << 5));
  }

  // cell threads: all 512 own (unit u_l of 8, batch bq); c-state in registers
  const int u_l = tid & 7, bq = tid >> 3;
  const int ubase = (isX ? (bid << 3) : ((bid - 128) << 3));  // unit base
  float bias[4];
  {
    const float* bsrc = isX ? b0 : b1;
#pragma unroll
    for (int g = 0; g < 4; ++g) bias[g] = bsrc[((ubase + u_l) << 2) + g];
  }
  float cv = 0.f;

  __shared__ float red[4][32][68];  // [K-split][gatecol][batch]; 68 = align

  __syncthreads();  // s_agg/s_xcd visible

  unsigned* rel = flags + 272 + (s_xcd << 4);  // this XCD's release word

  for (int k = 0; k <= 512; ++k) {
    if (isX) {
      if (k < 512) {
        // ---- A(k): gates0 = [x_k | h0(k-1)] @ W0cat^T ----
        const __hip_bfloat16* h0prev = h0buf + ((size_t)(k & 1) << 16);
        f32x4 a0 = {0.f, 0.f, 0.f, 0.f}, a1 = a0, a2 = a0, a3 = a0;
#pragma unroll
        for (int c = 0; c < 10; ++c) {
          const int k0 = ks * 320 + (c << 5);
          const __hip_bfloat16* ab;
          size_t rs;
          if (k0 < 256) {  // x part
            ab = xbf + ((size_t)k << 14) + k0 + (kq << 3);
            rs = 256;
          } else {         // h part
            ab = h0prev + (k0 - 256) + (kq << 3);
            rs = 1024;
          }
          bf16x8 f0 = *(const bf16x8*)(ab + (size_t)col * rs);
          bf16x8 f1 = *(const bf16x8*)(ab + (size_t)(16 + col) * rs);
          bf16x8 f2 = *(const bf16x8*)(ab + (size_t)(32 + col) * rs);
          bf16x8 f3 = *(const bf16x8*)(ab + (size_t)(48 + col) * rs);
          a0 = __builtin_amdgcn_mfma_f32_16x16x32_bf16(f0, wa[c], a0, 0, 0, 0);
          a1 = __builtin_amdgcn_mfma_f32_16x16x32_bf16(f1, wa[c], a1, 0, 0, 0);
          a2 = __builtin_amdgcn_mfma_f32_16x16x32_bf16(f2, wa[c], a2, 0, 0, 0);
          a3 = __builtin_amdgcn_mfma_f32_16x16x32_bf16(f3, wa[c], a3, 0, 0, 0);
        }
        const int rc = (ch << 4) + col;
        *(f32x4*)&red[ks][rc][(kq << 2)] = a0;
        *(f32x4*)&red[ks][rc][16 + (kq << 2)] = a1;
        *(f32x4*)&red[ks][rc][32 + (kq << 2)] = a2;
        *(f32x4*)&red[ks][rc][48 + (kq << 2)] = a3;
        __syncthreads();
        {  // cell 0 (all 512 threads) -> publish h0(k) to slot (k+1)&1
          float gg[4];
#pragma unroll
          for (int g = 0; g < 4; ++g) {
            float v = bias[g];
#pragma unroll
            for (int ww = 0; ww < 4; ++ww) v += red[ww][(u_l << 2) + g][bq];
            gg[g] = v;
          }
          float cn = sigm(gg[1]) * cv + sigm(gg[0]) * ftanh(gg[2]);
          cv = cn;
          vstore_bf16(h0buf + ((size_t)((k + 1) & 1) << 16) +
                          ((size_t)bq << 10) + ubase + u_l,
                      sigm(gg[3]) * ftanh(cn));
        }
        __syncthreads();  // red free before proj overwrites it
      }
      // ---- proj out(k-3) from h1(k-3) in slot (k-3)%3 == k%3 ----
      if (isproj && k >= 3)
        do_proj(h1buf + (((size_t)(k % 3)) << 16), wp,
                (float(*)[16][68])red, blin, out, pcol, pbat, k - 3, tid, w,
                col, kq);
    } else {
      if (k >= 1) {
        // ---- B(k-1): gates1 = [h0(k-1) | h1(k-2)] @ W1^T ----
        const __hip_bfloat16* h0cur = h0buf + ((size_t)(k & 1) << 16);
        const __hip_bfloat16* h1prev = h1buf + ((size_t)((k + 1) % 3) << 16);
        f32x4 a0 = {0.f, 0.f, 0.f, 0.f}, a1 = a0, a2 = a0, a3 = a0;
#pragma unroll
        for (int c = 0; c < 16; ++c) {
          const int k0 = (ks << 9) + (c << 5);
          const __hip_bfloat16* ab =
              ((k0 < 1024) ? h0cur + k0 : h1prev + (k0 - 1024)) + (kq << 3);
          bf16x8 f0 = *(const bf16x8*)(ab + ((size_t)col << 10));
          bf16x8 f1 = *(const bf16x8*)(ab + ((size_t)(16 + col) << 10));
          bf16x8 f2 = *(const bf16x8*)(ab + ((size_t)(32 + col) << 10));
          bf16x8 f3 = *(const bf16x8*)(ab + ((size_t)(48 + col) << 10));
          a0 = __builtin_amdgcn_mfma_f32_16x16x32_bf16(f0, wb[c], a0, 0, 0, 0);
          a1 = __builtin_amdgcn_mfma_f32_16x16x32_bf16(f1, wb[c], a1, 0, 0, 0);
          a2 = __builtin_amdgcn_mfma_f32_16x16x32_bf16(f2, wb[c], a2, 0, 0, 0);
          a3 = __builtin_amdgcn_mfma_f32_16x16x32_bf16(f3, wb[c], a3, 0, 0, 0);
        }
        const int rc = (ch << 4) + col;
        *(f32x4*)&red[ks][rc][(kq << 2)] = a0;
        *(f32x4*)&red[ks][rc][16 + (kq << 2)] = a1;
        *(f32x4*)&red[ks][rc][32 + (kq << 2)] = a2;
        *(f32x4*)&red[ks][rc][48 + (kq << 2)] = a3;
        __syncthreads();
        {  // cell 1 -> publish h1(k-1) to slot (k+2)%3
          float gg[4];
#pragma unroll
          for (int g = 0; g < 4; ++g) {
            float v = bias[g];
#pragma unroll
            for (int ww = 0; ww < 4; ++ww) v += red[ww][(u_l << 2) + g][bq];
            gg[g] = v;
          }
          float cn = sigm(gg[1]) * cv + sigm(gg[0]) * ftanh(gg[2]);
          cv = cn;
          vstore_bf16(h1buf + ((size_t)((k + 2) % 3) << 16) +
                          ((size_t)bq << 10) + ubase + u_l,
                      sigm(gg[3]) * ftanh(cn));
        }
      }
    }

    // ---- drain + arrive + hierarchical release (R9 machinery) ----
    __builtin_amdgcn_s_waitcnt(0);  // per-wave: publishes / proj-outs drained
    __syncthreads();                // all waves drained before the flag
    if (tid == 0)
      __hip_atomic_store(&flags[bid], (unsigned)(k + 1), __ATOMIC_RELAXED,
                         __HIP_MEMORY_SCOPE_AGENT);
    if (w == 0) {
      const unsigned tgt = (unsigned)(k + 1);
      if (s_agg) {
        const u64* fq = (const u64*)flags;
        for (;;) {
          u64 q0 = __hip_atomic_load(&fq[2 * lane], __ATOMIC_RELAXED,
                                     __HIP_MEMORY_SCOPE_AGENT);
          u64 q1 = __hip_atomic_load(&fq[2 * lane + 1], __ATOMIC_RELAXED,
                                     __HIP_MEMORY_SCOPE_AGENT);
          int ok = ((unsigned)q0 >= tgt) & ((unsigned)(q0 >> 32) >= tgt) &
                   ((unsigned)q1 >= tgt) & ((unsigned)(q1 >> 32) >= tgt);
          if (__all(ok)) break;
          __builtin_amdgcn_s_sleep(1);
        }
        // per-XCD leader fence: waitcnt + L1/L2 inv (proven codegen)
        __builtin_amdgcn_fence(__ATOMIC_ACQUIRE, "agent");
        if (lane == 0)
          __hip_atomic_store(rel, tgt, __ATOMIC_RELAXED,
                             __HIP_MEMORY_SCOPE_AGENT);
      } else {
        while (__hip_atomic_load(rel, __ATOMIC_RELAXED,
                                 __HIP_MEMORY_SCOPE_AGENT) < tgt)
          __builtin_amdgcn_s_sleep(1);
        if (bid < 8) {
          __builtin_amdgcn_fence(__ATOMIC_ACQUIRE, "agent");  // belt
        } else {
          __builtin_amdgcn_sched_barrier(0);
          asm volatile("buffer_inv" ::: "memory");  // L1-only inv
          __builtin_amdgcn_sched_barrier(0);
        }
      }
    }
    __syncthreads();
  }

  // ---- tails: proj(510) slot 0, proj(511) slot 1 (fenced at k=512) ----
  if (isproj) {
    do_proj(h1buf, wp, (float(*)[16][68])red, blin, out, pcol, pbat, 510, tid,
            w, col, kq);
    __syncthreads();  // red reuse barrier
    do_proj(h1buf + ((size_t)1 << 16), wp, (float(*)[16][68])red, blin, out,
            pcol, pbat, 511, tid, w, col, kq);
  }
}

// ---------------- host launch ----------------

extern "C" void kernel_launch(void* const* d_in, const int* in_sizes, int n_in,
                              void* d_out, int out_size, void* d_ws, size_t ws_size,
                              hipStream_t stream) {
  const float* z = (const float*)d_in[0];
  const float* x = (const float*)d_in[1];
  const float* Wih0 = (const float*)d_in[2];
  const float* Whh0 = (const float*)d_in[3];
  const float* bih0 = (const float*)d_in[4];
  const float* bhh0 = (const float*)d_in[5];
  const float* Wih1 = (const float*)d_in[6];
  const float* Whh1 = (const float*)d_in[7];
  const float* bih1 = (const float*)d_in[8];
  const float* bhh1 = (const float*)d_in[9];
  const float* Wlin = (const float*)d_in[10];
  const float* blin = (const float*)d_in[11];
  float* out = (float*)d_out;

  char* ws = (char*)d_ws;
  __hip_bfloat16* W0 = (__hip_bfloat16*)(ws);                // 10,485,760 B
  __hip_bfloat16* W1 = (__hip_bfloat16*)(ws + 10485760);     // 17,825,792 B
  __hip_bfloat16* xbf = (__hip_bfloat16*)(ws + 28311552);    // 16,777,216 B
  float* b0 = (float*)(ws + 45088768);                       // 16,384 B
  float* b1 = (float*)(ws + 45105152);                       // 16,384 B
  __hip_bfloat16* h0buf = (__hip_bfloat16*)(ws + 45121536);  // 262,144 B (2 slots)
  __hip_bfloat16* h1buf = (__hip_bfloat16*)(ws + 45383680);  // 393,216 B (3 slots)
  unsigned* flags = (unsigned*)(ws + 45776896);              // 4,096 B

  hipMemsetAsync(flags, 0, 4096, stream);  // ws is re-poisoned every call
  prep_w0<<<4096, 256, 0, stream>>>(Wih0, Whh0, W0);
  prep_w1<<<4096, 256, 0, stream>>>(Wih1, Whh1, Wlin, W1);
  prep_x<<<4096, 256, 0, stream>>>(x, xbf);
  prep_misc<<<288, 256, 0, stream>>>(bih0, bhh0, bih1, bhh1, z, b0, b1, h0buf,
                                     h1buf);

  k_persist<<<256, 512, 0, stream>>>(xbf, W0, W1, b0, b1, blin, h0buf, h1buf,
                                     out, flags);
}

// Round 9
// 8734.463 us; speedup vs baseline: 1.1607x; 1.0581x over previous
//
#include <hip/hip_runtime.h>
#include <hip/hip_bf16.h>
#include <math.h>

// LSTM decoder: B=64, T=512, IN=256, OUT=256, H=1024, 2 layers + linear head.
// Round 13 = R9 base + DEEP SLOT ROTATION to make the heavy L2-inv rare.
//  - h0/h1 each 8 slots (slot = t&7). An address is rewritten only every
//    8 steps and last read 6+ steps before rewrite -> any L2-inv in that
//    window preserves coherence. Heavy fence (agent acquire: waitcnt +
//    L1/L2 inv) now runs only on steps t%4==0, on XCD leaders + belt,
//    placed in the SHADOW window (post-cell0, pre-proj) — off the
//    critical path. Cheap L1 buffer_inv likewise only on t%4==0.
//  - Per-step barrier = drain -> flag -> poll -> release with NO cache op.
//  - L2 contents survive across steps: x[t+1] prefetch (R9) is now real;
//    weight/x lines stop being re-fetched from LLC every step.
//  - Everything else identical to R9 (best: 8848us).

typedef __attribute__((ext_vector_type(8))) short bf16x8;   // 8 x bf16
typedef __attribute__((ext_vector_type(4))) float f32x4;
typedef unsigned long long u64;

__device__ __forceinline__ float sigm(float v) {
  return 1.f / (1.f + __expf(-v));
}
__device__ __forceinline__ float ftanh(float v) {
  return 2.f / (1.f + __expf(-2.f * v)) - 1.f;
}

__device__ __forceinline__ unsigned short bf16_bits(float v) {
  __hip_bfloat16 hb = __float2bfloat16(v);
  unsigned short us;
  __builtin_memcpy(&us, &hb, 2);
  return us;
}

// write-through (sc0 sc1) 2B store
__device__ __forceinline__ void vstore_bf16(__hip_bfloat16* p, float v) {
  *(volatile unsigned short*)p = bf16_bits(v);
}

// ---------------- prep kernels (one-time per launch) ----------------

// W0cat[u*4+g][k] : k<256 -> Wih0[g*1024+u][k], else Whh0[g*1024+u][k-256]
__global__ __launch_bounds__(256) void prep_w0(const float* __restrict__ Wih0,
                                               const float* __restrict__ Whh0,
                                               __hip_bfloat16* __restrict__ W0) {
  const unsigned n = 4096u * 1280u;
  for (unsigned d = blockIdx.x * blockDim.x + threadIdx.x; d < n;
       d += blockDim.x * gridDim.x) {
    unsigned r = d / 1280u;
    unsigned k = d - r * 1280u;
    unsigned u = r >> 2, g = r & 3u;
    unsigned srow = g * 1024u + u;
    float v = (k < 256u) ? Wih0[(size_t)srow * 256u + k]
                         : Whh0[(size_t)srow * 1024u + (k - 256u)];
    W0[d] = __float2bfloat16(v);
  }
}

// W1ext[4352][2048]: rows<4096 reordered LSTM1 weights [Wih1|Whh1];
// rows 4096+o: [zeros(1024) | Wlin[o]]
__global__ __launch_bounds__(256) void prep_w1(const float* __restrict__ Wih1,
                                               const float* __restrict__ Whh1,
                                               const float* __restrict__ Wlin,
                                               __hip_bfloat16* __restrict__ W1) {
  const unsigned n = 4352u * 2048u;
  for (unsigned d = blockIdx.x * blockDim.x + threadIdx.x; d < n;
       d += blockDim.x * gridDim.x) {
    unsigned r = d >> 11;
    unsigned k = d & 2047u;
    float v;
    if (r < 4096u) {
      unsigned u = r >> 2, g = r & 3u;
      unsigned srow = g * 1024u + u;
      v = (k < 1024u) ? Wih1[(size_t)srow * 1024u + k]
                      : Whh1[(size_t)srow * 1024u + (k - 1024u)];
    } else {
      unsigned o = r - 4096u;
      v = (k < 1024u) ? 0.f : Wlin[(size_t)o * 1024u + (k - 1024u)];
    }
    W1[d] = __float2bfloat16(v);
  }
}

// xbf[t][b][k] = bf16( t==0 ? 0 : x[b][t-1][k] )   (teacher forcing shift)
__global__ __launch_bounds__(256) void prep_x(const float* __restrict__ x,
                                              __hip_bfloat16* __restrict__ xbf) {
  const unsigned n = 512u * 64u * 256u;
  for (unsigned d = blockIdx.x * blockDim.x + threadIdx.x; d < n;
       d += blockDim.x * gridDim.x) {
    unsigned t = d >> 14;
    unsigned b = (d >> 8) & 63u;
    unsigned k = d & 255u;
    float v = (t == 0u) ? 0.f : x[((size_t)b * 512u + (t - 1u)) * 256u + k];
    xbf[d] = __float2bfloat16(v);
  }
}

// biases (gate-interleaved, bih+bhh combined) + h init: h0[-1] and h1[-1]
// both live in slot (-1)&7 = 7.
__global__ __launch_bounds__(256) void prep_misc(
    const float* __restrict__ bih0, const float* __restrict__ bhh0,
    const float* __restrict__ bih1, const float* __restrict__ bhh1,
    const float* __restrict__ z, float* __restrict__ b0, float* __restrict__ b1,
    __hip_bfloat16* __restrict__ h0buf, __hip_bfloat16* __restrict__ h1buf) {
  for (int i = blockIdx.x * blockDim.x + threadIdx.x; i < 73728;
       i += blockDim.x * gridDim.x) {
    if (i < 4096) {
      int u = i >> 2, g = i & 3;
      b0[i] = bih0[g * 1024 + u] + bhh0[g * 1024 + u];
    } else if (i < 8192) {
      int r = i - 4096;
      int u = r >> 2, g = r & 3;
      b1[r] = bih1[g * 1024 + u] + bhh1[g * 1024 + u];
    } else {
      int j = i - 8192;  // 0..65535
      float zv = z[j];
      vstore_bf16(h0buf + 7 * 65536 + j, zv);           // h0 slot 7
      vstore_bf16(h1buf + 7 * 65536 + j, zv);           // h1 slot 7
    }
  }
}

// ---------------- projection helper (blocks 64..127) ----------------
// out[pbat*16 .. +16, t_out, pcol*16 .. +16) = h1p @ Wlin^T + blin

__device__ __forceinline__ void do_proj(const __hip_bfloat16* __restrict__ h1p,
                                        const bf16x8* wp, float (*red)[16][68],
                                        const float* __restrict__ blin,
                                        float* __restrict__ out, int pcol,
                                        int pbat, int t_out, int tid, int w,
                                        int col, int kq) {
  f32x4 a0 = {0.f, 0.f, 0.f, 0.f};
  const __hip_bfloat16* ab =
      h1p + ((size_t)((pbat << 4) + col) << 10) + (w << 7) + (kq << 3);
#pragma unroll
  for (int c = 0; c < 4; ++c) {
    bf16x8 f = *(const bf16x8*)(ab + (c << 5));
    a0 = __builtin_amdgcn_mfma_f32_16x16x32_bf16(f, wp[c], a0, 0, 0, 0);
  }
  *(f32x4*)&red[w][col][(kq << 2)] = a0;
  __syncthreads();
  if (tid < 256) {
    int o_l = tid & 15, b = tid >> 4;  // b: 0..15
    float v = blin[(pcol << 4) + o_l];
#pragma unroll
    for (int ww = 0; ww < 8; ++ww) v += red[ww][o_l][b];
    out[(((size_t)((pbat << 4) + b) << 9) + (size_t)t_out) * 256 + (pcol << 4) +
        o_l] = v;
  }
  // callers follow with a block-wide barrier before red is rewritten
}

// ---------------- persistent kernel ----------------

__global__ __launch_bounds__(512) void k_persist(
    const __hip_bfloat16* __restrict__ xbf, const __hip_bfloat16* __restrict__ W0,
    const __hip_bfloat16* __restrict__ W1, const float* __restrict__ b0,
    const float* __restrict__ b1, const float* __restrict__ blin,
    __hip_bfloat16* __restrict__ h0buf, __hip_bfloat16* __restrict__ h1buf,
    float* __restrict__ out, unsigned* __restrict__ flags) {
  const int tid = threadIdx.x;
  const int lane = tid & 63;
  const int w = tid >> 6;          // wave id = K-split index (0..7)
  const int bid = blockIdx.x;
  const int cb = bid << 4;         // 16 gate-columns owned by this block
  const int col = lane & 15;
  const int kq = lane >> 4;
  const int n = cb + col;
  const bool isproj = (bid >= 64 && bid < 128);
  const int pcol = bid & 15;       // proj: out-col tile
  const int pbat = (bid >> 4) & 3; // proj: batch tile

  // ---- per-XCD aggregator election ----
  // flags layout (words): [0..255] flags; [256..263] lead; [272+16x] release.
  __shared__ int s_agg, s_xcd;
  {
    unsigned* lead = flags + 256;
    if (tid == 0) {
      unsigned xcc = 0;
      asm volatile("s_getreg_b32 %0, hwreg(HW_REG_XCC_ID)" : "=s"(xcc));
      xcc &= 7u;
      unsigned old = __hip_atomic_fetch_add(&lead[xcc], 1u, __ATOMIC_RELAXED,
                                            __HIP_MEMORY_SCOPE_AGENT);
      s_agg = (old == 0u) ? 1 : 0;
      s_xcd = (int)xcc;
    }
  }

  // ---- weights -> registers (persist across all 512 steps) ----
  bf16x8 wa[5], wb[8], wp[4];
  {
    const __hip_bfloat16* p = W0 + (size_t)n * 1280 + w * 160 + (kq << 3);
#pragma unroll
    for (int c = 0; c < 5; ++c) wa[c] = *(const bf16x8*)(p + (c << 5));
  }
  {
    const __hip_bfloat16* p = W1 + ((size_t)n << 11) + (w << 8) + (kq << 3);
#pragma unroll
    for (int c = 0; c < 8; ++c) wb[c] = *(const bf16x8*)(p + (c << 5));
  }
  if (isproj) {
    const __hip_bfloat16* p = W1 +
        ((size_t)(4096 + (pcol << 4) + col) << 11) + 1024 + (w << 7) + (kq << 3);
#pragma unroll
    for (int c = 0; c < 4; ++c) wp[c] = *(const bf16x8*)(p + (c << 5));
  } else {
#pragma unroll
    for (int c = 0; c < 4; ++c) wp[c] = bf16x8{0, 0, 0, 0, 0, 0, 0, 0};
  }

  // cell threads: tid<256 own (unit u_l of 4, batch bq); c-state in registers
  const int u_l = tid & 3, bq = tid >> 2;
  float bias0[4], bias1[4];
  if (tid < 256) {
#pragma unroll
    for (int g = 0; g < 4; ++g) {
      bias0[g] = b0[cb + (u_l << 2) + g];
      bias1[g] = b1[cb + (u_l << 2) + g];
    }
  }
  float c0v = 0.f, c1v = 0.f;

  __shared__ float red[8][16][68];  // K-partials; 68 keeps 16B alignment

  __syncthreads();  // s_agg/s_xcd visible to all waves

  unsigned* rel = flags + 272 + (s_xcd << 4);  // this XCD's release word

  for (int t = 0; t < 512; ++t) {
    // 8-slot rotation: h0(t) -> slot t&7; h1(t) -> slot t&7.
    const __hip_bfloat16* h0prev = h0buf + ((size_t)((t + 7) & 7) << 16);
    const __hip_bfloat16* h0cur = h0buf + ((size_t)(t & 7) << 16);
    const __hip_bfloat16* h1prev = h1buf + ((size_t)((t + 7) & 7) << 16);

    // ======== phase A: gates0 = [x_t | h0prev] @ W0cat^T ========
    // h0prev L2-warm from B(t-1); x_t L2-warm from last step's prefetch
    // (prefetch now SURVIVES: heavy inv only every 4th step).
    {
      f32x4 a0 = {0.f, 0.f, 0.f, 0.f}, a1 = a0, a2 = a0, a3 = a0;
#pragma unroll
      for (int c = 0; c < 5; ++c) {
        const int k0 = w * 160 + (c << 5);
        const __hip_bfloat16* ab;
        size_t rs;
        if (k0 < 256) {  // x part
          ab = xbf + ((size_t)t << 14) + k0 + (kq << 3);
          rs = 256;
        } else {         // h part
          ab = h0prev + (k0 - 256) + (kq << 3);
          rs = 1024;
        }
        bf16x8 f0 = *(const bf16x8*)(ab + (size_t)col * rs);
        bf16x8 f1 = *(const bf16x8*)(ab + (size_t)(16 + col) * rs);
        bf16x8 f2 = *(const bf16x8*)(ab + (size_t)(32 + col) * rs);
        bf16x8 f3 = *(const bf16x8*)(ab + (size_t)(48 + col) * rs);
        a0 = __builtin_amdgcn_mfma_f32_16x16x32_bf16(f0, wa[c], a0, 0, 0, 0);
        a1 = __builtin_amdgcn_mfma_f32_16x16x32_bf16(f1, wa[c], a1, 0, 0, 0);
        a2 = __builtin_amdgcn_mfma_f32_16x16x32_bf16(f2, wa[c], a2, 0, 0, 0);
        a3 = __builtin_amdgcn_mfma_f32_16x16x32_bf16(f3, wa[c], a3, 0, 0, 0);
      }
      *(f32x4*)&red[w][col][(kq << 2)] = a0;
      *(f32x4*)&red[w][col][16 + (kq << 2)] = a1;
      *(f32x4*)&red[w][col][32 + (kq << 2)] = a2;
      *(f32x4*)&red[w][col][48 + (kq << 2)] = a3;
    }
    __syncthreads();
    if (tid < 256) {  // 8-way K-reduce + LSTM cell 0 -> direct 2B publish
      float gg[4];
#pragma unroll
      for (int g = 0; g < 4; ++g) {
        float v = bias0[g];
#pragma unroll
        for (int ww = 0; ww < 8; ++ww) v += red[ww][(u_l << 2) + g][bq];
        gg[g] = v;
      }
      float cn = sigm(gg[1]) * c0v + sigm(gg[0]) * ftanh(gg[2]);
      c0v = cn;
      vstore_bf16((__hip_bfloat16*)h0cur + ((size_t)bq << 10) + (cb >> 2) + u_l,
                  sigm(gg[3]) * ftanh(cn));
    }
    __syncthreads();  // red free; publish stores issued

    // ---- PERIODIC cache hygiene in the shadow (every 4th step only).
    // Slot addresses are reused every 8 steps and last read >=6 steps
    // before rewrite; any inv inside that window preserves coherence.
    if ((t & 3) == 0 && w == 0) {
      __builtin_amdgcn_sched_barrier(0);
      if (s_agg || bid >= 248) {
        // heavy: waitcnt + L1+L2 inv (proven codegen) — leaders + belt
        __builtin_amdgcn_fence(__ATOMIC_ACQUIRE, "agent");
      } else {
        asm volatile("buffer_inv" ::: "memory");  // L1-only, drain-free
      }
      __builtin_amdgcn_sched_barrier(0);
    }

    // ---- window work: proj out[t-2] OR x[t+1] L2-prefetch ----
    if (isproj && t >= 2) {
      // h1[t-2] lives in slot (t-2)&7 == (t+6)&7
      do_proj(h1buf + (((size_t)((t + 6) & 7)) << 16), wp, red, blin, out,
              pcol, pbat, t - 2, tid, w, col, kq);
    } else if (w < 2 && t < 511) {
      // warm L1/L2 with next step's x tile (survives 3/4 of steps now)
      const char* px = (const char*)(xbf + ((size_t)(t + 1) << 14));
      const int idx = (w << 6) | lane;  // 0..127
#pragma unroll
      for (int i = 0; i < 4; ++i) {
        unsigned v = *(const unsigned*)(px + ((idx + (i << 7)) << 6));
        asm volatile("" ::"v"(v));  // keep the load
      }
    }

    // ---- drain + arrive + hierarchical release (NO cache op here) ----
    __builtin_amdgcn_s_waitcnt(0);  // per-wave: publishes / proj-outs drained
    __syncthreads();                // all waves drained before the flag
    if (tid == 0)
      __hip_atomic_store(&flags[bid], (unsigned)(t + 1), __ATOMIC_RELAXED,
                         __HIP_MEMORY_SCOPE_AGENT);
    if (w == 0) {
      const unsigned tgt = (unsigned)(t + 1);
      if (s_agg) {
        // aggregator: the ONLY all-256 poller on this XCD
        const u64* fq = (const u64*)flags;
        for (;;) {
          u64 q0 = __hip_atomic_load(&fq[2 * lane], __ATOMIC_RELAXED,
                                     __HIP_MEMORY_SCOPE_AGENT);
          u64 q1 = __hip_atomic_load(&fq[2 * lane + 1], __ATOMIC_RELAXED,
                                     __HIP_MEMORY_SCOPE_AGENT);
          int ok = ((unsigned)q0 >= tgt) & ((unsigned)(q0 >> 32) >= tgt) &
                   ((unsigned)q1 >= tgt) & ((unsigned)(q1 >> 32) >= tgt);
          if (__all(ok)) break;
          __builtin_amdgcn_s_sleep(1);
        }
        if (lane == 0)
          __hip_atomic_store(rel, tgt, __ATOMIC_RELAXED,
                             __HIP_MEMORY_SCOPE_AGENT);
      } else {
        // followers poll ONE word: their XCD's release line
        while (__hip_atomic_load(rel, __ATOMIC_RELAXED,
                                 __HIP_MEMORY_SCOPE_AGENT) < tgt)
          __builtin_amdgcn_s_sleep(1);
      }
    }
    __syncthreads();

    // ======== phase B: gates1 = [h0cur | h1prev] @ W1^T ========
    {
      const __hip_bfloat16* ab =
          ((w < 4) ? h0cur : h1prev) + ((w & 3) << 8) + (kq << 3);
      f32x4 a0 = {0.f, 0.f, 0.f, 0.f}, a1 = a0, a2 = a0, a3 = a0;
#pragma unroll
      for (int c = 0; c < 8; ++c) {
        const __hip_bfloat16* p = ab + (c << 5);
        bf16x8 f0 = *(const bf16x8*)(p + ((size_t)col << 10));
        bf16x8 f1 = *(const bf16x8*)(p + ((size_t)(16 + col) << 10));
        bf16x8 f2 = *(const bf16x8*)(p + ((size_t)(32 + col) << 10));
        bf16x8 f3 = *(const bf16x8*)(p + ((size_t)(48 + col) << 10));
        a0 = __builtin_amdgcn_mfma_f32_16x16x32_bf16(f0, wb[c], a0, 0, 0, 0);
        a1 = __builtin_amdgcn_mfma_f32_16x16x32_bf16(f1, wb[c], a1, 0, 0, 0);
        a2 = __builtin_amdgcn_mfma_f32_16x16x32_bf16(f2, wb[c], a2, 0, 0, 0);
        a3 = __builtin_amdgcn_mfma_f32_16x16x32_bf16(f3, wb[c], a3, 0, 0, 0);
      }
      *(f32x4*)&red[w][col][(kq << 2)] = a0;
      *(f32x4*)&red[w][col][16 + (kq << 2)] = a1;
      *(f32x4*)&red[w][col][32 + (kq << 2)] = a2;
      *(f32x4*)&red[w][col][48 + (kq << 2)] = a3;
    }
    __syncthreads();
    if (tid < 256) {  // 8-way K-reduce + LSTM cell 1 -> direct 2B publish
      float gg[4];
#pragma unroll
      for (int g = 0; g < 4; ++g) {
        float v = bias1[g];
#pragma unroll
        for (int ww = 0; ww < 8; ++ww) v += red[ww][(u_l << 2) + g][bq];
        gg[g] = v;
      }
      float cn = sigm(gg[1]) * c1v + sigm(gg[0]) * ftanh(gg[2]);
      c1v = cn;
      // h1[t] -> slot t&7 (drains at next step's pre-flag waitcnt)
      vstore_bf16(h1buf + ((size_t)(t & 7) << 16) + ((size_t)bq << 10) +
                      (cb >> 2) + u_l,
                  sigm(gg[3]) * ftanh(cn));
    }
    __syncthreads();  // red safe for next iteration's phase A
  }

  // ---- tail: h1[510] in slot 6, h1[511] in slot 7 (just published) ----
  __builtin_amdgcn_s_waitcnt(0);  // per-wave drain of h1[511] publishes
  __syncthreads();
  if (tid == 0)
    __hip_atomic_store(&flags[bid], 513u, __ATOMIC_RELAXED,
                       __HIP_MEMORY_SCOPE_AGENT);
  if (w == 0 && s_agg) {
    const u64* fq = (const u64*)flags;
    for (;;) {
      u64 q0 = __hip_atomic_load(&fq[2 * lane], __ATOMIC_RELAXED,
                                 __HIP_MEMORY_SCOPE_AGENT);
      u64 q1 = __hip_atomic_load(&fq[2 * lane + 1], __ATOMIC_RELAXED,
                                 __HIP_MEMORY_SCOPE_AGENT);
      int ok = ((unsigned)q0 >= 513u) & ((unsigned)(q0 >> 32) >= 513u) &
               ((unsigned)q1 >= 513u) & ((unsigned)(q1 >> 32) >= 513u);
      if (__all(ok)) break;
      __builtin_amdgcn_s_sleep(1);
    }
    __builtin_amdgcn_fence(__ATOMIC_ACQUIRE, "agent");
    if (lane == 0)
      __hip_atomic_store(rel, 513u, __ATOMIC_RELAXED,
                         __HIP_MEMORY_SCOPE_AGENT);
  }
  if (!isproj) return;
  if (w == 0 && !s_agg) {
    while (__hip_atomic_load(rel, __ATOMIC_RELAXED,
                             __HIP_MEMORY_SCOPE_AGENT) < 513u)
      __builtin_amdgcn_s_sleep(1);
    // one-time full acquire before reading h1[510]/h1[511] (belt)
    __builtin_amdgcn_fence(__ATOMIC_ACQUIRE, "agent");
  }
  __syncthreads();
  do_proj(h1buf + ((size_t)6 << 16), wp, red, blin, out, pcol, pbat, 510, tid,
          w, col, kq);
  __syncthreads();  // red reuse barrier between the two tail projections
  do_proj(h1buf + ((size_t)7 << 16), wp, red, blin, out, pcol, pbat, 511, tid,
          w, col, kq);
}

// ---------------- host launch ----------------

extern "C" void kernel_launch(void* const* d_in, const int* in_sizes, int n_in,
                              void* d_out, int out_size, void* d_ws, size_t ws_size,
                              hipStream_t stream) {
  const float* z = (const float*)d_in[0];
  const float* x = (const float*)d_in[1];
  const float* Wih0 = (const float*)d_in[2];
  const float* Whh0 = (const float*)d_in[3];
  const float* bih0 = (const float*)d_in[4];
  const float* bhh0 = (const float*)d_in[5];
  const float* Wih1 = (const float*)d_in[6];
  const float* Whh1 = (const float*)d_in[7];
  const float* bih1 = (const float*)d_in[8];
  const float* bhh1 = (const float*)d_in[9];
  const float* Wlin = (const float*)d_in[10];
  const float* blin = (const float*)d_in[11];
  float* out = (float*)d_out;

  char* ws = (char*)d_ws;
  __hip_bfloat16* W0 = (__hip_bfloat16*)(ws);                // 10,485,760 B
  __hip_bfloat16* W1 = (__hip_bfloat16*)(ws + 10485760);     // 17,825,792 B
  __hip_bfloat16* xbf = (__hip_bfloat16*)(ws + 28311552);    // 16,777,216 B
  float* b0 = (float*)(ws + 45088768);                       // 16,384 B
  float* b1 = (float*)(ws + 45105152);                       // 16,384 B
  __hip_bfloat16* h0buf = (__hip_bfloat16*)(ws + 45121536);  // 1,048,576 B (8 slots)
  __hip_bfloat16* h1buf = (__hip_bfloat16*)(ws + 46170112);  // 1,048,576 B (8 slots)
  unsigned* flags = (unsigned*)(ws + 47218688);              // 4,096 B

  hipMemsetAsync(flags, 0, 4096, stream);  // ws is re-poisoned every call
  prep_w0<<<4096, 256, 0, stream>>>(Wih0, Whh0, W0);
  prep_w1<<<4096, 256, 0, stream>>>(Wih1, Whh1, Wlin, W1);
  prep_x<<<4096, 256, 0, stream>>>(x, xbf);
  prep_misc<<<288, 256, 0, stream>>>(bih0, bhh0, bih1, bhh1, z, b0, b1, h0buf,
                                     h1buf);

  k_persist<<<256, 512, 0, stream>>>(xbf, W0, W1, b0, b1, blin, h0buf, h1buf,
                                     out, flags);
}

// Round 10
// 8631.873 us; speedup vs baseline: 1.1745x; 1.0119x over previous
//
#include <hip/hip_runtime.h>
#include <hip/hip_bf16.h>
#include <math.h>

// LSTM decoder: B=64, T=512, IN=256, OUT=256, H=1024, 2 layers + linear head.
// Round 14: CONCURRENT A/B wave-split. B(k-1) and A(k) are independent
// given release(k-1) — run them simultaneously on disjoint waves:
//   waves 0-3: B(k-1) = [h0(k-1)|h1(k-2)] @ W1  (K=2048, 4-way split)
//   waves 4-7: A(k)   = [x(k)|h0(k-1)]   @ W0  (K=1280, 4-way split)
//   cells in parallel: tid<256 cell0 (reduce A-parts, publish h0(k));
//                      tid>=256 cell1 (reduce B-parts, publish h1(k-1))
//   ONE drain+flag+poll per iteration covers both publishes.
// Removes one compute phase + one cell phase from the serial per-step
// chain (R13: release->B->cell1->A->cell0->drain->flag->poll).
// Kept from R13 (best, 8734us): 8-slot rotation, fence every 4th iter
// (leaders+belt heavy, others L1-only), hierarchical aggregator/release
// barrier, proj in window (blocks 64..127), 513 iterations k=0..512.

typedef __attribute__((ext_vector_type(8))) short bf16x8;   // 8 x bf16
typedef __attribute__((ext_vector_type(4))) float f32x4;
typedef unsigned long long u64;

__device__ __forceinline__ float sigm(float v) {
  return 1.f / (1.f + __expf(-v));
}
__device__ __forceinline__ float ftanh(float v) {
  return 2.f / (1.f + __expf(-2.f * v)) - 1.f;
}

__device__ __forceinline__ unsigned short bf16_bits(float v) {
  __hip_bfloat16 hb = __float2bfloat16(v);
  unsigned short us;
  __builtin_memcpy(&us, &hb, 2);
  return us;
}

// write-through (sc0 sc1) 2B store
__device__ __forceinline__ void vstore_bf16(__hip_bfloat16* p, float v) {
  *(volatile unsigned short*)p = bf16_bits(v);
}

// ---------------- prep kernels (one-time per launch) ----------------

// W0cat[u*4+g][k] : k<256 -> Wih0[g*1024+u][k], else Whh0[g*1024+u][k-256]
__global__ __launch_bounds__(256) void prep_w0(const float* __restrict__ Wih0,
                                               const float* __restrict__ Whh0,
                                               __hip_bfloat16* __restrict__ W0) {
  const unsigned n = 4096u * 1280u;
  for (unsigned d = blockIdx.x * blockDim.x + threadIdx.x; d < n;
       d += blockDim.x * gridDim.x) {
    unsigned r = d / 1280u;
    unsigned k = d - r * 1280u;
    unsigned u = r >> 2, g = r & 3u;
    unsigned srow = g * 1024u + u;
    float v = (k < 256u) ? Wih0[(size_t)srow * 256u + k]
                         : Whh0[(size_t)srow * 1024u + (k - 256u)];
    W0[d] = __float2bfloat16(v);
  }
}

// W1ext[4352][2048]: rows<4096 reordered LSTM1 weights [Wih1|Whh1];
// rows 4096+o: [zeros(1024) | Wlin[o]]
__global__ __launch_bounds__(256) void prep_w1(const float* __restrict__ Wih1,
                                               const float* __restrict__ Whh1,
                                               const float* __restrict__ Wlin,
                                               __hip_bfloat16* __restrict__ W1) {
  const unsigned n = 4352u * 2048u;
  for (unsigned d = blockIdx.x * blockDim.x + threadIdx.x; d < n;
       d += blockDim.x * gridDim.x) {
    unsigned r = d >> 11;
    unsigned k = d & 2047u;
    float v;
    if (r < 4096u) {
      unsigned u = r >> 2, g = r & 3u;
      unsigned srow = g * 1024u + u;
      v = (k < 1024u) ? Wih1[(size_t)srow * 1024u + k]
                      : Whh1[(size_t)srow * 1024u + (k - 1024u)];
    } else {
      unsigned o = r - 4096u;
      v = (k < 1024u) ? 0.f : Wlin[(size_t)o * 1024u + (k - 1024u)];
    }
    W1[d] = __float2bfloat16(v);
  }
}

// xbf[t][b][k] = bf16( t==0 ? 0 : x[b][t-1][k] )   (teacher forcing shift)
__global__ __launch_bounds__(256) void prep_x(const float* __restrict__ x,
                                              __hip_bfloat16* __restrict__ xbf) {
  const unsigned n = 512u * 64u * 256u;
  for (unsigned d = blockIdx.x * blockDim.x + threadIdx.x; d < n;
       d += blockDim.x * gridDim.x) {
    unsigned t = d >> 14;
    unsigned b = (d >> 8) & 63u;
    unsigned k = d & 255u;
    float v = (t == 0u) ? 0.f : x[((size_t)b * 512u + (t - 1u)) * 256u + k];
    xbf[d] = __float2bfloat16(v);
  }
}

// biases (gate-interleaved, bih+bhh combined) + h init: h0[-1] and h1[-1]
// both live in slot (-1)&7 = 7.
__global__ __launch_bounds__(256) void prep_misc(
    const float* __restrict__ bih0, const float* __restrict__ bhh0,
    const float* __restrict__ bih1, const float* __restrict__ bhh1,
    const float* __restrict__ z, float* __restrict__ b0, float* __restrict__ b1,
    __hip_bfloat16* __restrict__ h0buf, __hip_bfloat16* __restrict__ h1buf) {
  for (int i = blockIdx.x * blockDim.x + threadIdx.x; i < 73728;
       i += blockDim.x * gridDim.x) {
    if (i < 4096) {
      int u = i >> 2, g = i & 3;
      b0[i] = bih0[g * 1024 + u] + bhh0[g * 1024 + u];
    } else if (i < 8192) {
      int r = i - 4096;
      int u = r >> 2, g = r & 3;
      b1[r] = bih1[g * 1024 + u] + bhh1[g * 1024 + u];
    } else {
      int j = i - 8192;  // 0..65535
      float zv = z[j];
      vstore_bf16(h0buf + 7 * 65536 + j, zv);           // h0 slot 7
      vstore_bf16(h1buf + 7 * 65536 + j, zv);           // h1 slot 7
    }
  }
}

// ---------------- projection helper (blocks 64..127) ----------------
// out[pbat*16 .. +16, t_out, pcol*16 .. +16) = h1p @ Wlin^T + blin
// K=1024 split over all 8 waves.

__device__ __forceinline__ void do_proj(const __hip_bfloat16* __restrict__ h1p,
                                        const bf16x8* wp, float (*red)[16][68],
                                        const float* __restrict__ blin,
                                        float* __restrict__ out, int pcol,
                                        int pbat, int t_out, int tid, int w,
                                        int col, int kq) {
  f32x4 a0 = {0.f, 0.f, 0.f, 0.f};
  const __hip_bfloat16* ab =
      h1p + ((size_t)((pbat << 4) + col) << 10) + (w << 7) + (kq << 3);
#pragma unroll
  for (int c = 0; c < 4; ++c) {
    bf16x8 f = *(const bf16x8*)(ab + (c << 5));
    a0 = __builtin_amdgcn_mfma_f32_16x16x32_bf16(f, wp[c], a0, 0, 0, 0);
  }
  *(f32x4*)&red[w][col][(kq << 2)] = a0;
  __syncthreads();
  if (tid < 256) {
    int o_l = tid & 15, b = tid >> 4;  // b: 0..15
    float v = blin[(pcol << 4) + o_l];
#pragma unroll
    for (int ww = 0; ww < 8; ++ww) v += red[ww][o_l][b];
    out[(((size_t)((pbat << 4) + b) << 9) + (size_t)t_out) * 256 + (pcol << 4) +
        o_l] = v;
  }
  // callers follow with a block-wide barrier before red is rewritten
}

// ---------------- persistent kernel ----------------

__global__ __launch_bounds__(512) void k_persist(
    const __hip_bfloat16* __restrict__ xbf, const __hip_bfloat16* __restrict__ W0,
    const __hip_bfloat16* __restrict__ W1, const float* __restrict__ b0,
    const float* __restrict__ b1, const float* __restrict__ blin,
    __hip_bfloat16* __restrict__ h0buf, __hip_bfloat16* __restrict__ h1buf,
    float* __restrict__ out, unsigned* __restrict__ flags) {
  const int tid = threadIdx.x;
  const int lane = tid & 63;
  const int w = tid >> 6;          // wave id 0..7; 0-3 = B-waves, 4-7 = A-waves
  const int bid = blockIdx.x;
  const int cb = bid << 4;         // 16 gate-columns owned by this block
  const int col = lane & 15;
  const int kq = lane >> 4;
  const int n = cb + col;
  const bool isproj = (bid >= 64 && bid < 128);
  const int pcol = bid & 15;       // proj: out-col tile
  const int pbat = (bid >> 4) & 3; // proj: batch tile

  // ---- per-XCD aggregator election ----
  // flags layout (words): [0..255] flags; [256..263] lead; [272+16x] release.
  __shared__ int s_agg, s_xcd;
  {
    unsigned* lead = flags + 256;
    if (tid == 0) {
      unsigned xcc = 0;
      asm volatile("s_getreg_b32 %0, hwreg(HW_REG_XCC_ID)" : "=s"(xcc));
      xcc &= 7u;
      unsigned old = __hip_atomic_fetch_add(&lead[xcc], 1u, __ATOMIC_RELAXED,
                                            __HIP_MEMORY_SCOPE_AGENT);
      s_agg = (old == 0u) ? 1 : 0;
      s_xcd = (int)xcc;
    }
  }

  // ---- weights -> registers (role-dependent; persist across all steps) ----
  bf16x8 wreg[16], wp[4];
  if (w < 4) {
    // B-wave: W1 row n, K-slice [w*512, w*512+512)
    const __hip_bfloat16* p = W1 + ((size_t)n << 11) + (w << 9) + (kq << 3);
#pragma unroll
    for (int c = 0; c < 16; ++c) wreg[c] = *(const bf16x8*)(p + (c << 5));
  } else {
    // A-wave: W0 row n, K-slice [(w-4)*320, +320)
    const __hip_bfloat16* p = W0 + (size_t)n * 1280 + (w - 4) * 320 + (kq << 3);
#pragma unroll
    for (int c = 0; c < 10; ++c) wreg[c] = *(const bf16x8*)(p + (c << 5));
#pragma unroll
    for (int c = 10; c < 16; ++c) wreg[c] = bf16x8{0, 0, 0, 0, 0, 0, 0, 0};
  }
  if (isproj) {
    const __hip_bfloat16* p = W1 +
        ((size_t)(4096 + (pcol << 4) + col) << 11) + 1024 + (w << 7) + (kq << 3);
#pragma unroll
    for (int c = 0; c < 4; ++c) wp[c] = *(const bf16x8*)(p + (c << 5));
  } else {
#pragma unroll
    for (int c = 0; c < 4; ++c) wp[c] = bf16x8{0, 0, 0, 0, 0, 0, 0, 0};
  }

  // cell threads: tid<256 -> cell0 (h0), tid>=256 -> cell1 (h1).
  const int tc = tid & 255;
  const int u_l = tc & 3, bq = tc >> 2;
  const bool is0 = (tid < 256);
  float bias[4];
  {
    const float* bsrc = is0 ? b0 : b1;
#pragma unroll
    for (int g = 0; g < 4; ++g) bias[g] = bsrc[cb + (u_l << 2) + g];
  }
  float cv = 0.f;  // c0 state on tid<256, c1 state on tid>=256

  __shared__ float red[8][16][68];  // [wave][gatecol][batch]; 68 = align

  __syncthreads();  // s_agg/s_xcd visible to all waves

  unsigned* rel = flags + 272 + (s_xcd << 4);  // this XCD's release word

  for (int k = 0; k <= 512; ++k) {
    const __hip_bfloat16* h0p = h0buf + ((size_t)((k + 7) & 7) << 16);   // h0(k-1)
    const __hip_bfloat16* h1pp = h1buf + ((size_t)((k + 6) & 7) << 16);  // h1(k-2)

    // ======== concurrent compute: B(k-1) on waves 0-3, A(k) on 4-7 ======
    if (w < 4) {
      if (k >= 1) {
        f32x4 a0 = {0.f, 0.f, 0.f, 0.f}, a1 = a0, a2 = a0, a3 = a0;
#pragma unroll
        for (int c = 0; c < 16; ++c) {
          const int k0 = (w << 9) + (c << 5);
          const __hip_bfloat16* ab =
              ((k0 < 1024) ? h0p + k0 : h1pp + (k0 - 1024)) + (kq << 3);
          bf16x8 f0 = *(const bf16x8*)(ab + ((size_t)col << 10));
          bf16x8 f1 = *(const bf16x8*)(ab + ((size_t)(16 + col) << 10));
          bf16x8 f2 = *(const bf16x8*)(ab + ((size_t)(32 + col) << 10));
          bf16x8 f3 = *(const bf16x8*)(ab + ((size_t)(48 + col) << 10));
          a0 = __builtin_amdgcn_mfma_f32_16x16x32_bf16(f0, wreg[c], a0, 0, 0, 0);
          a1 = __builtin_amdgcn_mfma_f32_16x16x32_bf16(f1, wreg[c], a1, 0, 0, 0);
          a2 = __builtin_amdgcn_mfma_f32_16x16x32_bf16(f2, wreg[c], a2, 0, 0, 0);
          a3 = __builtin_amdgcn_mfma_f32_16x16x32_bf16(f3, wreg[c], a3, 0, 0, 0);
        }
        *(f32x4*)&red[w][col][(kq << 2)] = a0;
        *(f32x4*)&red[w][col][16 + (kq << 2)] = a1;
        *(f32x4*)&red[w][col][32 + (kq << 2)] = a2;
        *(f32x4*)&red[w][col][48 + (kq << 2)] = a3;
      }
    } else {
      if (k < 512) {
        f32x4 a0 = {0.f, 0.f, 0.f, 0.f}, a1 = a0, a2 = a0, a3 = a0;
#pragma unroll
        for (int c = 0; c < 10; ++c) {
          const int k0 = (w - 4) * 320 + (c << 5);
          const __hip_bfloat16* ab;
          size_t rs;
          if (k0 < 256) {  // x part
            ab = xbf + ((size_t)k << 14) + k0 + (kq << 3);
            rs = 256;
          } else {         // h part
            ab = h0p + (k0 - 256) + (kq << 3);
            rs = 1024;
          }
          bf16x8 f0 = *(const bf16x8*)(ab + (size_t)col * rs);
          bf16x8 f1 = *(const bf16x8*)(ab + (size_t)(16 + col) * rs);
          bf16x8 f2 = *(const bf16x8*)(ab + (size_t)(32 + col) * rs);
          bf16x8 f3 = *(const bf16x8*)(ab + (size_t)(48 + col) * rs);
          a0 = __builtin_amdgcn_mfma_f32_16x16x32_bf16(f0, wreg[c], a0, 0, 0, 0);
          a1 = __builtin_amdgcn_mfma_f32_16x16x32_bf16(f1, wreg[c], a1, 0, 0, 0);
          a2 = __builtin_amdgcn_mfma_f32_16x16x32_bf16(f2, wreg[c], a2, 0, 0, 0);
          a3 = __builtin_amdgcn_mfma_f32_16x16x32_bf16(f3, wreg[c], a3, 0, 0, 0);
        }
        *(f32x4*)&red[w][col][(kq << 2)] = a0;
        *(f32x4*)&red[w][col][16 + (kq << 2)] = a1;
        *(f32x4*)&red[w][col][32 + (kq << 2)] = a2;
        *(f32x4*)&red[w][col][48 + (kq << 2)] = a3;
      }
    }
    __syncthreads();

    // ======== parallel cells: cell0 on tid<256, cell1 on tid>=256 ========
    if (is0) {
      if (k < 512) {  // reduce A-parts (red[4..7]) -> h0(k) -> slot k&7
        float gg[4];
#pragma unroll
        for (int g = 0; g < 4; ++g) {
          float v = bias[g];
#pragma unroll
          for (int ww = 0; ww < 4; ++ww) v += red[4 + ww][(u_l << 2) + g][bq];
          gg[g] = v;
        }
        float cn = sigm(gg[1]) * cv + sigm(gg[0]) * ftanh(gg[2]);
        cv = cn;
        vstore_bf16(h0buf + ((size_t)(k & 7) << 16) + ((size_t)bq << 10) +
                        (cb >> 2) + u_l,
                    sigm(gg[3]) * ftanh(cn));
      }
    } else {
      if (k >= 1) {   // reduce B-parts (red[0..3]) -> h1(k-1) -> slot (k+7)&7
        float gg[4];
#pragma unroll
        for (int g = 0; g < 4; ++g) {
          float v = bias[g];
#pragma unroll
          for (int ww = 0; ww < 4; ++ww) v += red[ww][(u_l << 2) + g][bq];
          gg[g] = v;
        }
        float cn = sigm(gg[1]) * cv + sigm(gg[0]) * ftanh(gg[2]);
        cv = cn;
        vstore_bf16(h1buf + ((size_t)((k + 7) & 7) << 16) + ((size_t)bq << 10) +
                        (cb >> 2) + u_l,
                    sigm(gg[3]) * ftanh(cn));
      }
    }
    __syncthreads();  // cells done reading red (proj clobbers it next)

    // ---- rare cache hygiene (every 4th iter; 8-slot reuse window >=6) ----
    if ((k & 3) == 0 && w == 0) {
      __builtin_amdgcn_sched_barrier(0);
      if (s_agg || bid >= 248) {
        __builtin_amdgcn_fence(__ATOMIC_ACQUIRE, "agent");  // heavy L1+L2 inv
      } else {
        asm volatile("buffer_inv" ::: "memory");            // L1-only
      }
      __builtin_amdgcn_sched_barrier(0);
    }

    // ---- window: proj out(k-2) from h1(k-2) (flagged at barrier k-1) ----
    if (isproj && k >= 2)
      do_proj(h1pp, wp, red, blin, out, pcol, pbat, k - 2, tid, w, col, kq);

    // ---- drain + arrive + hierarchical release ----
    __builtin_amdgcn_s_waitcnt(0);  // own publishes / proj-outs drained
    __syncthreads();                // all waves drained before the flag
    if (tid == 0)
      __hip_atomic_store(&flags[bid], (unsigned)(k + 1), __ATOMIC_RELAXED,
                         __HIP_MEMORY_SCOPE_AGENT);
    if (w == 0) {
      const unsigned tgt = (unsigned)(k + 1);
      if (s_agg) {
        const u64* fq = (const u64*)flags;
        for (;;) {
          u64 q0 = __hip_atomic_load(&fq[2 * lane], __ATOMIC_RELAXED,
                                     __HIP_MEMORY_SCOPE_AGENT);
          u64 q1 = __hip_atomic_load(&fq[2 * lane + 1], __ATOMIC_RELAXED,
                                     __HIP_MEMORY_SCOPE_AGENT);
          int ok = ((unsigned)q0 >= tgt) & ((unsigned)(q0 >> 32) >= tgt) &
                   ((unsigned)q1 >= tgt) & ((unsigned)(q1 >> 32) >= tgt);
          if (__all(ok)) break;
          __builtin_amdgcn_s_sleep(1);
        }
        if (lane == 0)
          __hip_atomic_store(rel, tgt, __ATOMIC_RELAXED,
                             __HIP_MEMORY_SCOPE_AGENT);
      } else {
        while (__hip_atomic_load(rel, __ATOMIC_RELAXED,
                                 __HIP_MEMORY_SCOPE_AGENT) < tgt)
          __builtin_amdgcn_s_sleep(1);
      }
    }
    __syncthreads();
  }

  // ---- tail: proj out(511) from h1(511) (slot 7, visible at release 512).
  if (!isproj) return;
  if (w == 0)  // belt: purge any stale slot-7 lines before the read
    __builtin_amdgcn_fence(__ATOMIC_ACQUIRE, "agent");
  __syncthreads();
  do_proj(h1buf + ((size_t)7 << 16), wp, red, blin, out, pcol, pbat, 511, tid,
          w, col, kq);
}

// ---------------- host launch ----------------

extern "C" void kernel_launch(void* const* d_in, const int* in_sizes, int n_in,
                              void* d_out, int out_size, void* d_ws, size_t ws_size,
                              hipStream_t stream) {
  const float* z = (const float*)d_in[0];
  const float* x = (const float*)d_in[1];
  const float* Wih0 = (const float*)d_in[2];
  const float* Whh0 = (const float*)d_in[3];
  const float* bih0 = (const float*)d_in[4];
  const float* bhh0 = (const float*)d_in[5];
  const float* Wih1 = (const float*)d_in[6];
  const float* Whh1 = (const float*)d_in[7];
  const float* bih1 = (const float*)d_in[8];
  const float* bhh1 = (const float*)d_in[9];
  const float* Wlin = (const float*)d_in[10];
  const float* blin = (const float*)d_in[11];
  float* out = (float*)d_out;

  char* ws = (char*)d_ws;
  __hip_bfloat16* W0 = (__hip_bfloat16*)(ws);                // 10,485,760 B
  __hip_bfloat16* W1 = (__hip_bfloat16*)(ws + 10485760);     // 17,825,792 B
  __hip_bfloat16* xbf = (__hip_bfloat16*)(ws + 28311552);    // 16,777,216 B
  float* b0 = (float*)(ws + 45088768);                       // 16,384 B
  float* b1 = (float*)(ws + 45105152);                       // 16,384 B
  __hip_bfloat16* h0buf = (__hip_bfloat16*)(ws + 45121536);  // 1,048,576 B (8 slots)
  __hip_bfloat16* h1buf = (__hip_bfloat16*)(ws + 46170112);  // 1,048,576 B (8 slots)
  unsigned* flags = (unsigned*)(ws + 47218688);              // 4,096 B

  hipMemsetAsync(flags, 0, 4096, stream);  // ws is re-poisoned every call
  prep_w0<<<4096, 256, 0, stream>>>(Wih0, Whh0, W0);
  prep_w1<<<4096, 256, 0, stream>>>(Wih1, Whh1, Wlin, W1);
  prep_x<<<4096, 256, 0, stream>>>(x, xbf);
  prep_misc<<<288, 256, 0, stream>>>(bih0, bhh0, bih1, bhh1, z, b0, b1, h0buf,
                                     h1buf);

  k_persist<<<256, 512, 0, stream>>>(xbf, W0, W1, b0, b1, blin, h0buf, h1buf,
                                     out, flags);
}